// Round 12
// baseline (124.380 us; speedup 1.0000x reference)
//
#include <hip/hip_runtime.h>
#include <math.h>
#include <stdint.h>

#define B_SZ 2048
#define N_SZ 16384
#define D_SZ 64
#define P_SZ 5

#define BM 128
#define BN 128
#define NCB (N_SZ / BN)   // 128
#define NREP 5            // profiling replication (idempotent stores; last write wins)
#define INVLN2 1.44269504088896340736f
#define LN2    0.69314718055994530942f

typedef __bf16 bf16x8 __attribute__((ext_vector_type(8)));
typedef __bf16 bf16x4 __attribute__((ext_vector_type(4)));
typedef float f32x4 __attribute__((ext_vector_type(4)));

// ws layout (float units): only the per-(item-block, user) partial sums
#define WS_PART 0     // [NCB][B_SZ] = 128*2048 floats = 1 MB

__device__ __forceinline__ float fexp2(float x) { return __builtin_amdgcn_exp2f(x); }

// swizzled byte offset of 16B-group g16 in row `row` of a [128][64]bf16 tile
#define SWZ(row, g16) (((row) << 7) + ((((g16) ^ ((row) & 7))) << 4))

__global__ __launch_bounds__(256, 4) void dist_k(const float* __restrict__ uem,
                                                 const float* __restrict__ vem,
                                                 const float* __restrict__ target,
                                                 const int* __restrict__ iidx,
                                                 const int* __restrict__ pidx,
                                                 float* __restrict__ ws) {
    __shared__ __bf16 Ut[BM * D_SZ];         // 16 KB, swizzled rows
    __shared__ __bf16 Vt[BN * D_SZ];         // 16 KB, swizzled rows
    __shared__ float u2s[BM];
    __shared__ float msgs[BM];
    __shared__ float colv2[BN];
    __shared__ int ids[BM * 6];              // p0..p4 + own id per user
    __shared__ int colid[BN];
    __shared__ unsigned int bloom[512];      // 16384-bit filter; ALIASED as part[256] after bar3
    __shared__ unsigned long long flagw[2];  // per wi-half flagged-column bits

    const int t = threadIdx.x;
    const int orig = blockIdx.x & (NCB * (B_SZ / BM) - 1);   // virtual block (rep = blockIdx.x >> 11)
    const int bx = (orig & 7) * 16 + ((orig >> 3) & 15);     // item block (XCD slab)
    const int by = orig >> 7;                                // user block
    const int brow = by * BM, bcol = bx * BN;

    bloom[t] = 0u;
    bloom[256 + t] = 0u;

    // ---- fused stage: fp32 global -> (norms via shfl) + bf16 swizzled LDS ----
    {
        const float4* su = (const float4*)(uem + (size_t)brow * D_SZ);
        const float4* sv = (const float4*)(vem + (size_t)bcol * D_SZ);
        for (int i = 0; i < 8; ++i) {
            int f = i * 256 + t;
            int row = f >> 4, seg = f & 15, g = seg >> 1, p = seg & 1;
            float4 x = su[f];
            float4 y = sv[f];
            float nu = x.x * x.x + x.y * x.y + x.z * x.z + x.w * x.w;
            float nv = y.x * y.x + y.y * y.y + y.z * y.z + y.w * y.w;
#pragma unroll
            for (int o = 1; o < 16; o <<= 1) {
                nu += __shfl_xor(nu, o);
                nv += __shfl_xor(nv, o);
            }
            if (seg == 0) {
                u2s[row] = nu;
                colv2[row] = nv;
            }
            *(bf16x4*)((char*)Ut + SWZ(row, g) + p * 8) =
                (bf16x4){(__bf16)x.x, (__bf16)x.y, (__bf16)x.z, (__bf16)x.w};
            *(bf16x4*)((char*)Vt + SWZ(row, g) + p * 8) =
                (bf16x4){(__bf16)y.x, (__bf16)y.y, (__bf16)y.z, (__bf16)y.w};
        }
    }
    if (t < BM) {
        int U = brow + t;
        float tg = target[U];
        float sg = (tg > 0.f) ? 1.f : ((tg < 0.f) ? -1.f : 0.f);
        msgs[t] = -0.5f * INVLN2 * sg;       // log2-domain sign factor (<= 0)
        const int* pp = pidx + (size_t)U * P_SZ;
        int* d = &ids[t * 6];
        d[0] = pp[0]; d[1] = pp[1]; d[2] = pp[2]; d[3] = pp[3]; d[4] = pp[4];
        d[5] = iidx[U];
        colid[t] = iidx[bcol + t];
    }
    __syncthreads();                         // bar1: tiles + scalars complete
    if (t < BM) {
        const int* d = &ids[t * 6];
#pragma unroll
        for (int j = 0; j < 6; ++j) {
            unsigned int h = (unsigned)d[j] & 16383u;
            atomicOr(&bloom[h >> 5], 1u << (h & 31));
        }
    }
    __syncthreads();                         // bar2: bloom built
    if ((t >> 6) < 2) {                      // waves 0,1: flag bits per wi-half
        int l = t & 63;
        unsigned int h = (unsigned)colid[(t >> 6) * 64 + l] & 16383u;
        bool f = (bloom[h >> 5] >> (h & 31)) & 1u;
        unsigned long long bal = __ballot(f);
        if (l == 0) flagw[t >> 6] = bal;
    }

    // ---- MFMA: A=items, B=users, frags from swizzled LDS ----
    const int w = t >> 6, l = t & 63;
    const int wi = w >> 1, wu = w & 1, lr = l & 15, kg = l >> 4;
    const char* UtB = (const char*)Ut;
    const char* VtB = (const char*)Vt;
    f32x4 acc[4][4];                         // [it][ut]
#pragma unroll
    for (int it = 0; it < 4; ++it)
#pragma unroll
        for (int ut = 0; ut < 4; ++ut)
            acc[it][ut] = (f32x4){0.f, 0.f, 0.f, 0.f};
#pragma unroll
    for (int kk = 0; kk < 2; ++kk) {
        bf16x8 afk[4];
#pragma unroll
        for (int it = 0; it < 4; ++it)
            afk[it] = *(const bf16x8*)(VtB + SWZ(wi * 64 + it * 16 + lr, kk * 4 + kg));
#pragma unroll
        for (int ut = 0; ut < 4; ++ut) {
            bf16x8 bu = *(const bf16x8*)(UtB + SWZ(wu * 64 + ut * 16 + lr, kk * 4 + kg));
#pragma unroll
            for (int it = 0; it < 4; ++it)
                acc[it][ut] = __builtin_amdgcn_mfma_f32_16x16x32_bf16(afk[it], bu, acc[it][ut], 0, 0, 0);
        }
    }
    __syncthreads();                         // bar3: flagw visible; bloom dead -> alias as part
    float* part = (float*)bloom;             // [2][BM] floats (1 KB of the 2 KB region)

    // ---- epilogue: branch-free exp2 sum; rare flagged columns subtracted ----
    f32x4 v2q[4];
    unsigned nib[4];
    const unsigned long long fm = flagw[wi];
#pragma unroll
    for (int it = 0; it < 4; ++it) {
        v2q[it] = *(const f32x4*)&colv2[wi * 64 + it * 16 + kg * 4];
        nib[it] = ((unsigned)(fm >> (it * 16 + kg * 4))) & 0xFu;
    }
#pragma unroll
    for (int ut = 0; ut < 4; ++ut) {
        const int ur = wu * 64 + ut * 16 + lr;   // user = C col (lane&15)
        const float u2r = u2s[ur];
        const float msg2 = msgs[ur];
        const float c1 = -2.f * msg2;            // >= 0
        float Sl = 0.f;
#pragma unroll
        for (int it = 0; it < 4; ++it) {
            f32x4 bt;
#pragma unroll
            for (int r = 0; r < 4; ++r) bt[r] = (u2r + v2q[it][r]) * msg2;
#pragma unroll
            for (int r = 0; r < 4; ++r) {
                float v = fminf(fmaf(c1, acc[it][ut][r], bt[r]), 0.f);
                Sl += fexp2(v);
            }
            if (nib[it]) {                       // rare: flagged column in this group
                const int* q = &ids[ur * 6];
#pragma unroll
                for (int r = 0; r < 4; ++r) {
                    if ((nib[it] >> r) & 1u) {
                        int c = colid[wi * 64 + it * 16 + kg * 4 + r];
                        if ((c == q[0]) | (c == q[1]) | (c == q[2]) |
                            (c == q[3]) | (c == q[4]) | (c == q[5])) {
                            float v = fminf(fmaf(c1, acc[it][ut][r], bt[r]), 0.f);
                            Sl -= fexp2(v);      // exact cancel of masked term
                        }
                    }
                }
            }
        }
        Sl += __shfl_xor(Sl, 16);
        Sl += __shfl_xor(Sl, 32);
        if (kg == 0) part[wi * BM + ur] = Sl;    // unique slot per (wi, user)
    }
    __syncthreads();                         // bar4: partials in LDS
    if (t < BM)
        ws[WS_PART + (size_t)bx * B_SZ + brow + t] = part[t] + part[BM + t];
}

// wave per row: merge 128 partials + exact fp32 diagonal + ce
__global__ __launch_bounds__(256) void finish_k(const float* __restrict__ uem,
                                                const float* __restrict__ vem,
                                                const float* __restrict__ target,
                                                const float* __restrict__ ws,
                                                float* __restrict__ out) {
    const int wv = threadIdx.x >> 6, l = threadIdx.x & 63;
    const int r = blockIdx.x * 4 + wv;

    float S = ws[WS_PART + (size_t)l * B_SZ + r] +
              ws[WS_PART + (size_t)(64 + l) * B_SZ + r];
#pragma unroll
    for (int o = 1; o < 64; o <<= 1) S += __shfl_xor(S, o);

    float d2l = 0.f;
    if (l < 16) {
        float4 a = ((const float4*)(uem + (size_t)r * D_SZ))[l];
        float4 b = ((const float4*)(vem + (size_t)r * D_SZ))[l];
        float dx = a.x - b.x, dy = a.y - b.y, dz = a.z - b.z, dw = a.w - b.w;
        d2l = dx * dx + dy * dy + dz * dz + dw * dw;
    }
#pragma unroll
    for (int o = 1; o < 16; o <<= 1) d2l += __shfl_xor(d2l, o);

    __shared__ float cred[4];
    if (l == 0) {
        float tg = target[r];
        float sg = (tg > 0.f) ? 1.f : ((tg < 0.f) ? -1.f : 0.f);
        float p2 = -0.5f * INVLN2 * sg * d2l;          // diagonal logit, log2 domain
        float ce = LN2 * (__log2f(fexp2(p2) + S) - p2);
        cred[wv] = ce * fabsf(tg);
    }
    __syncthreads();
    if (threadIdx.x == 0)
        atomicAdd(out, cred[0] + cred[1] + cred[2] + cred[3]);
}

extern "C" void kernel_launch(void* const* d_in, const int* in_sizes, int n_in,
                              void* d_out, int out_size, void* d_ws, size_t ws_size,
                              hipStream_t stream) {
    const float* uem = (const float*)d_in[0];
    const float* vem = (const float*)d_in[1];
    const float* target = (const float*)d_in[2];
    const int* iidx = (const int*)d_in[3];
    const int* pidx = (const int*)d_in[4];
    float* ws = (float*)d_ws;
    float* out = (float*)d_out;

    hipMemsetAsync(out, 0, sizeof(float), stream);

    // Profiling build: NREP in-kernel replication (idempotent stores -> identical
    // output; one ~150 us dispatch that finally tops the rocprof table).
    dist_k<<<dim3(NREP * NCB * (B_SZ / BM)), dim3(256), 0, stream>>>(uem, vem, target, iidx, pidx, ws);

    finish_k<<<dim3(B_SZ / 4), dim3(256), 0, stream>>>(uem, vem, target, ws, out);
}

// Round 13
// 43.944 us; speedup vs baseline: 2.8304x; 2.8304x over previous
//
#include <hip/hip_runtime.h>
#include <math.h>
#include <stdint.h>

#define B_SZ 2048
#define N_SZ 16384
#define D_SZ 64
#define P_SZ 5

#define BM 128
#define BN 128
#define NCB (N_SZ / BN)   // 128
#define INVLN2 1.44269504088896340736f
#define LN2    0.69314718055994530942f

typedef __bf16 bf16x8 __attribute__((ext_vector_type(8)));
typedef __bf16 bf16x4 __attribute__((ext_vector_type(4)));
typedef float f32x4 __attribute__((ext_vector_type(4)));

// ws layout (float units)
#define WS_PART 0                           // [NCB][B_SZ] partial S sums (1 MB)
#define WS_U2   (WS_PART + NCB * B_SZ)      // [2048]
#define WS_V2   (WS_U2 + B_SZ)              // [16384]
#define WS_UBF  (WS_V2 + N_SZ)              // bf16[2048][64], swizzled rows
#define WS_VBF  (WS_UBF + B_SZ * D_SZ / 2)  // bf16[16384][64], swizzled rows

__device__ __forceinline__ float fexp2(float x) { return __builtin_amdgcn_exp2f(x); }

#define GLD_LDS(g, s) __builtin_amdgcn_global_load_lds( \
    (const __attribute__((address_space(1))) void*)(g), \
    (__attribute__((address_space(3))) void*)(s), 16, 0, 0)

// swizzled byte offset of 16B-group g16 in row `row` of a [128][64]bf16 tile
#define SWZ(row, g16) (((row) << 7) + ((((g16) ^ ((row) & 7))) << 4))

// ---- prep: fp32 -> swizzled bf16 rows + norms; thread 0 zeroes out[0] ----
__global__ __launch_bounds__(256) void prep_k(const float* __restrict__ uem,
                                              const float* __restrict__ vem,
                                              float* __restrict__ ws,
                                              float* __restrict__ out) {
    if (blockIdx.x == 0 && threadIdx.x == 0) out[0] = 0.f;
    const int rid = blockIdx.x * 16 + (threadIdx.x >> 4);
    const int seg = threadIdx.x & 15;
    const bool isU = rid < B_SZ;
    const int r = isU ? rid : rid - B_SZ;
    const float* src = (isU ? uem : vem) + (size_t)r * D_SZ;
    float4 x = ((const float4*)src)[seg];
    float nrm = x.x * x.x + x.y * x.y + x.z * x.z + x.w * x.w;
#pragma unroll
    for (int o = 1; o < 16; o <<= 1) nrm += __shfl_xor(nrm, o);
    uint16_t* dst = (uint16_t*)(ws + (isU ? WS_UBF : WS_VBF)) + (size_t)r * D_SZ;
    int g = seg >> 1, p = seg & 1, r7 = r & 7;
    int off = (((g ^ r7) << 3) + (p << 2));            // uint16 units
    bf16x4 h = {(__bf16)x.x, (__bf16)x.y, (__bf16)x.z, (__bf16)x.w};
    *(bf16x4*)(dst + off) = h;
    if (seg == 0) {
        if (isU) ws[WS_U2 + r] = nrm;
        else     ws[WS_V2 + r] = nrm;
    }
}

__global__ __launch_bounds__(256, 4) void dist_k(const float* __restrict__ target,
                                                 const int* __restrict__ iidx,
                                                 const int* __restrict__ pidx,
                                                 float* __restrict__ ws) {
    __shared__ __bf16 Ut[BM * D_SZ];         // 16 KB, swizzled rows
    __shared__ __bf16 Vt[BN * D_SZ];         // 16 KB, swizzled rows
    __shared__ float u2s[BM];
    __shared__ float msgs[BM];
    __shared__ float colv2[BN];
    __shared__ int ids[BM * 6];              // p0..p4 + own id per user
    __shared__ int colid[BN];
    __shared__ unsigned int bloom[512];      // 16384-bit filter; aliased as part[256] after bar3
    __shared__ unsigned long long flagw[2];  // per wi-half flagged-column bits

    const int t = threadIdx.x;
    const int orig = blockIdx.x;
    const int bx = (orig & 7) * 16 + ((orig >> 3) & 15);   // item block (XCD slab)
    const int by = orig >> 7;                              // user block
    const int brow = by * BM, bcol = bx * BN;

    const float* u2 = ws + WS_U2;
    const float* v2 = ws + WS_V2;
    const uint16_t* ubf = (const uint16_t*)(ws + WS_UBF);
    const uint16_t* vbf = (const uint16_t*)(ws + WS_VBF);

    const int w = t >> 6, l = t & 63;

    bloom[t] = 0u;
    bloom[256 + t] = 0u;

    // ---- staging: pure async copy of pre-swizzled bf16 (zero VALU math) ----
    {
        const char* gu = (const char*)(ubf + (size_t)brow * D_SZ) + w * 4096 + l * 16;
        const char* gv = (const char*)(vbf + (size_t)bcol * D_SZ) + w * 4096 + l * 16;
        char* lu = (char*)Ut + w * 4096;
        char* lv = (char*)Vt + w * 4096;
#pragma unroll
        for (int i = 0; i < 4; ++i) {
            GLD_LDS(gu + i * 1024, lu + i * 1024);
            GLD_LDS(gv + i * 1024, lv + i * 1024);
        }
    }
    if (t < BM) {
        int U = brow + t;
        float tg = target[U];
        float sg = (tg > 0.f) ? 1.f : ((tg < 0.f) ? -1.f : 0.f);
        u2s[t] = u2[U];
        msgs[t] = -0.5f * INVLN2 * sg;       // log2-domain sign factor (<= 0)
        const int* pp = pidx + (size_t)U * P_SZ;
        int* d = &ids[t * 6];
        d[0] = pp[0]; d[1] = pp[1]; d[2] = pp[2]; d[3] = pp[3]; d[4] = pp[4];
        d[5] = iidx[U];
        colid[t] = iidx[bcol + t];
        colv2[t] = v2[bcol + t];
    }
    __syncthreads();                         // bar1: tiles + scalars ready
    if (t < BM) {
        const int* d = &ids[t * 6];
#pragma unroll
        for (int j = 0; j < 6; ++j) {
            unsigned int h = (unsigned)d[j] & 16383u;
            atomicOr(&bloom[h >> 5], 1u << (h & 31));
        }
    }
    __syncthreads();                         // bar2: bloom built
    if (w < 2) {                             // waves 0,1: flag bits per wi-half
        unsigned int h = (unsigned)colid[w * 64 + l] & 16383u;
        bool f = (bloom[h >> 5] >> (h & 31)) & 1u;
        unsigned long long bal = __ballot(f);
        if (l == 0) flagw[w] = bal;
    }

    // ---- MFMA: A=items, B=users, frags from swizzled LDS ----
    const int wi = w >> 1, wu = w & 1, lr = l & 15, kg = l >> 4;
    const char* UtB = (const char*)Ut;
    const char* VtB = (const char*)Vt;
    f32x4 acc[4][4];                         // [it][ut]
#pragma unroll
    for (int it = 0; it < 4; ++it)
#pragma unroll
        for (int ut = 0; ut < 4; ++ut)
            acc[it][ut] = (f32x4){0.f, 0.f, 0.f, 0.f};
#pragma unroll
    for (int kk = 0; kk < 2; ++kk) {
        bf16x8 afk[4];
#pragma unroll
        for (int it = 0; it < 4; ++it)
            afk[it] = *(const bf16x8*)(VtB + SWZ(wi * 64 + it * 16 + lr, kk * 4 + kg));
#pragma unroll
        for (int ut = 0; ut < 4; ++ut) {
            bf16x8 bu = *(const bf16x8*)(UtB + SWZ(wu * 64 + ut * 16 + lr, kk * 4 + kg));
#pragma unroll
            for (int it = 0; it < 4; ++it)
                acc[it][ut] = __builtin_amdgcn_mfma_f32_16x16x32_bf16(afk[it], bu, acc[it][ut], 0, 0, 0);
        }
    }
    __syncthreads();                         // bar3: flagw visible; bloom dead -> alias as part
    float* part = (float*)bloom;             // [2][BM] floats

    // ---- epilogue: 5 VALU-class ops per element; flagged columns subtracted ----
    f32x4 v2q[4];
    unsigned nib[4];
    const unsigned long long fm = flagw[wi];
#pragma unroll
    for (int it = 0; it < 4; ++it) {
        v2q[it] = *(const f32x4*)&colv2[wi * 64 + it * 16 + kg * 4];
        nib[it] = ((unsigned)(fm >> (it * 16 + kg * 4))) & 0xFu;
    }
#pragma unroll
    for (int ut = 0; ut < 4; ++ut) {
        const int ur = wu * 64 + ut * 16 + lr;   // user = C col (lane&15)
        const float u2r = u2s[ur];
        const float msg2 = msgs[ur];
        const float c1 = -2.f * msg2;            // >= 0
        const float a0 = u2r * msg2;             // fold u2 into one fmaf chain
        float Sl = 0.f;
#pragma unroll
        for (int it = 0; it < 4; ++it) {
#pragma unroll
            for (int r = 0; r < 4; ++r) {
                float v = fminf(fmaf(c1, acc[it][ut][r], fmaf(msg2, v2q[it][r], a0)), 0.f);
                Sl += fexp2(v);
            }
            if (nib[it]) {                       // rare: flagged column in this group
                const int* q = &ids[ur * 6];
#pragma unroll
                for (int r = 0; r < 4; ++r) {
                    if ((nib[it] >> r) & 1u) {
                        int c = colid[wi * 64 + it * 16 + kg * 4 + r];
                        if ((c == q[0]) | (c == q[1]) | (c == q[2]) |
                            (c == q[3]) | (c == q[4]) | (c == q[5])) {
                            float v = fminf(fmaf(c1, acc[it][ut][r], fmaf(msg2, v2q[it][r], a0)), 0.f);
                            Sl -= fexp2(v);      // exact cancel of masked term
                        }
                    }
                }
            }
        }
        Sl += __shfl_xor(Sl, 16);
        Sl += __shfl_xor(Sl, 32);
        if (kg == 0) part[wi * BM + ur] = Sl;    // unique slot per (wi, user)
    }
    __syncthreads();                         // bar4: partials in LDS
    if (t < BM)
        ws[WS_PART + (size_t)bx * B_SZ + brow + t] = part[t] + part[BM + t];
}

// wave per row: merge 128 partials + exact fp32 diagonal + ce
__global__ __launch_bounds__(256) void finish_k(const float* __restrict__ uem,
                                                const float* __restrict__ vem,
                                                const float* __restrict__ target,
                                                const float* __restrict__ ws,
                                                float* __restrict__ out) {
    const int wv = threadIdx.x >> 6, l = threadIdx.x & 63;
    const int r = blockIdx.x * 4 + wv;

    float S = ws[WS_PART + (size_t)l * B_SZ + r] +
              ws[WS_PART + (size_t)(64 + l) * B_SZ + r];
#pragma unroll
    for (int o = 1; o < 64; o <<= 1) S += __shfl_xor(S, o);

    float d2l = 0.f;
    if (l < 16) {
        float4 a = ((const float4*)(uem + (size_t)r * D_SZ))[l];
        float4 b = ((const float4*)(vem + (size_t)r * D_SZ))[l];
        float dx = a.x - b.x, dy = a.y - b.y, dz = a.z - b.z, dw = a.w - b.w;
        d2l = dx * dx + dy * dy + dz * dz + dw * dw;
    }
#pragma unroll
    for (int o = 1; o < 16; o <<= 1) d2l += __shfl_xor(d2l, o);

    __shared__ float cred[4];
    if (l == 0) {
        float tg = target[r];
        float sg = (tg > 0.f) ? 1.f : ((tg < 0.f) ? -1.f : 0.f);
        float p2 = -0.5f * INVLN2 * sg * d2l;          // diagonal logit, log2 domain
        float ce = LN2 * (__log2f(fexp2(p2) + S) - p2);
        cred[wv] = ce * fabsf(tg);
    }
    __syncthreads();
    if (threadIdx.x == 0)
        atomicAdd(out, cred[0] + cred[1] + cred[2] + cred[3]);
}

extern "C" void kernel_launch(void* const* d_in, const int* in_sizes, int n_in,
                              void* d_out, int out_size, void* d_ws, size_t ws_size,
                              hipStream_t stream) {
    const float* uem = (const float*)d_in[0];
    const float* vem = (const float*)d_in[1];
    const float* target = (const float*)d_in[2];
    const int* iidx = (const int*)d_in[3];
    const int* pidx = (const int*)d_in[4];
    float* ws = (float*)d_ws;
    float* out = (float*)d_out;

    prep_k<<<dim3((B_SZ + N_SZ) / 16), dim3(256), 0, stream>>>(uem, vem, ws, out);

    dist_k<<<dim3(NCB * (B_SZ / BM)), dim3(256), 0, stream>>>(target, iidx, pidx, ws);

    finish_k<<<dim3(B_SZ / 4), dim3(256), 0, stream>>>(uem, vem, target, ws, out);
}